// Round 2
// baseline (19814.655 us; speedup 1.0000x reference)
//
#include <hip/hip_runtime.h>

#define TT 16384
#define BB 8
#define HH 512
#define CC 24
#define KK 100
#define NEGF (-3.0e38f)

// ---------------- GEMM: scoresT[b][c][t] = hs[b,t,:] @ W[:,c] + bias[c] ----------------
// One thread per (b,t) row; stores transposed (coalesced along t across lanes).
__global__ __launch_bounds__(256) void score_gemm(
    const float* __restrict__ hs, const float* __restrict__ W,
    const float* __restrict__ bias, float* __restrict__ scoresT) {
  const int row = blockIdx.x * 256 + threadIdx.x;  // row = b*TT + t
  const int bb = row >> 14;                        // TT = 2^14
  const int ti = row & (TT - 1);
  const float* x = hs + (long)row * HH;
  float acc[CC];
#pragma unroll
  for (int c = 0; c < CC; ++c) acc[c] = bias[c];
#pragma unroll 2
  for (int h0 = 0; h0 < HH; h0 += 4) {
    float4 xv = *reinterpret_cast<const float4*>(x + h0);
    const float* wp = W + h0 * CC;
#pragma unroll
    for (int c = 0; c < CC; ++c) acc[c] = fmaf(xv.x, wp[c], acc[c]);
#pragma unroll
    for (int c = 0; c < CC; ++c) acc[c] = fmaf(xv.y, wp[CC + c], acc[c]);
#pragma unroll
    for (int c = 0; c < CC; ++c) acc[c] = fmaf(xv.z, wp[2 * CC + c], acc[c]);
#pragma unroll
    for (int c = 0; c < CC; ++c) acc[c] = fmaf(xv.w, wp[3 * CC + c], acc[c]);
  }
#pragma unroll
  for (int c = 0; c < CC; ++c) scoresT[((bb * CC + c) << 14) + ti] = acc[c];
}

// ---------------- DPP helper (VALU-pipe cross-lane) ----------------
template <int CTRL>
__device__ __forceinline__ float dppf(float x) {
  return __int_as_float(__builtin_amdgcn_update_dpp(
      0, __float_as_int(x), CTRL, 0xF, 0xF, true));
}
// quad_perm [1,0,3,2] = 0xB1 (swap adjacent pair), row_shr:1 = 0x111,
// row_ror:1/2/4/8 = 0x121/0x122/0x124/0x128

// ---------------- Streaming semi-Markov CRF scan: ONE WAVE per batch ----------------
// Lane l: c = l>>1 (channel 0..23), h = l&1 (window half). Lanes 48..63 mirror c=23.
// Window (exp-domain, scale M[c]): h=0 holds 50 newest slots, h=1 the 50 older;
// ring-buffer via 50x-unrolled time loop (no shift ops). Pipelined: ring dot at
// step t produces drest[t+1] (k>=2 terms), overlapping the LDS x-gather latency.
__global__ __launch_bounds__(64, 1) void crf_scan(
    const float* __restrict__ scoresT, const float* __restrict__ trans,
    const float* __restrict__ db, const int* __restrict__ lengths,
    float* __restrict__ out) {
  const int b = blockIdx.x;
  const int l = threadIdx.x;
  const int cr = l >> 1;
  const bool active = cr < CC;
  const int c = active ? cr : (CC - 1);
  const int h = l & 1;
  __shared__ float xs[32];

  // duration weights: W0 = exp(db[k=1]); Wr[v] = exp(db[k-1 = 1+v+50h]) (0 beyond K)
  float W0 = __expf(db[c]);
  float Wr[50];
#pragma unroll
  for (int v = 0; v < 50; ++v) {
    int idx = 1 + v + 50 * h;
    Wr[v] = (idx < KK) ? __expf(db[idx * CC + c]) : 0.0f;
  }
  // transition columns: lane (c,h) covers c' = 12h..12h+11
  float ET[12];
#pragma unroll
  for (int m = 0; m < 12; ++m) ET[m] = __expf(trans[(12 * h + m) * CC + c]);

  int len = lengths[b];
  len = len < 1 ? 1 : (len > TT ? TT : len);

  float E[50];
#pragma unroll
  for (int j = 0; j < 50; ++j) E[j] = 0.0f;

  const float* sp = scoresT + (b * CC + c) * TT;
  // prefetch queue: Q0=(sc[i],sc[i+1]) Q1=(+2,+3) Q2=(+4,+5); refill 5 ahead
  float2 Q0 = *(const float2*)(sp + 0);
  float2 Q1 = *(const float2*)(sp + 2);
  float2 Q2 = *(const float2*)(sp + 4);

  float cum = 0.0f;     // cum[t][c]
  float u_prev = 0.0f;  // u[t-1] = msg[t-1] - cum[t-1]; u[0] = 0
  float M = 0.0f;       // per-channel window scale (monotone)
  float umax = 0.0f;    // max recent u, for next rescale
  float am = 0.0f;      // wave-uniform LSE scale (lagged max msg)
  float drest = 0.0f;   // k>=2 window sum for current step (scale M)

  int t = 1;
  for (;;) {
#pragma unroll
    for (int p = 0; p < 50; ++p) {
      // ---- score (i = t-1; p even <=> i even, since t0 = 1 mod 50 and 50 even)
      float sc = ((p & 1) == 0) ? Q0.x : Q0.y;
      cum += sc;

      // ---- periodic rescale (amortized); M monotone since u drifts upward
      if (p % 10 == 0) {
        float Mn = fmaxf(M, umax);
        float r = __expf(M - Mn);
#pragma unroll
        for (int j = 0; j < 50; ++j) E[j] *= r;
        drest *= r;
        M = Mn;
        umax = NEGF;
      }

      // ---- critical chain head: k=1 term + pipelined rest
      float enew = __expf(u_prev - M);
      float dot = fmaf(enew, W0, drest);           // full window sum, scale M
      float g = fminf(cum + M - am, 75.0f);        // clamp = overflow backstop
      float x = dot * __expf(g);                   // x = exp(alpha[t,c] - am)

      // ---- LDS exchange (single wave: in-order DS pipe, no barrier)
      if (active && h == 0) xs[c] = x;
      float4 x0 = *(const float4*)&xs[12 * h];
      float4 x1 = *(const float4*)&xs[12 * h + 4];
      float4 x2 = *(const float4*)&xs[12 * h + 8];

      // ---- ring insert: h=0 takes enew (time t-1); h=1 takes h=0's evictee (t-51)
      float evict = dppf<0x111>(E[p]);             // from lane l-1 (pre-overwrite)
      E[p] = h ? evict : enew;

      // ---- ring dot for NEXT step (k>=2), issues under the LDS latency
      float a0 = 0.f, a1 = 0.f, a2 = 0.f, a3 = 0.f;
#pragma unroll
      for (int j = 0; j < 50; ++j) {
        float w = Wr[(p - j + 50) % 50];
        if ((j & 3) == 0) a0 = fmaf(E[j], w, a0);
        else if ((j & 3) == 1) a1 = fmaf(E[j], w, a1);
        else if ((j & 3) == 2) a2 = fmaf(E[j], w, a2);
        else a3 = fmaf(E[j], w, a3);
      }
      float part = (a0 + a1) + (a2 + a3);

      // ---- matvec: y[c] = sum_{c'} x[c'] * exp(T[c',c]) (pair-split over h)
      float ya = x0.x * ET[0];
      float yb = x0.y * ET[1];
      float yc = x0.z * ET[2];
      float yd = x0.w * ET[3];
      ya = fmaf(x1.x, ET[4], ya);
      yb = fmaf(x1.y, ET[5], yb);
      yc = fmaf(x1.z, ET[6], yc);
      yd = fmaf(x1.w, ET[7], yd);
      ya = fmaf(x2.x, ET[8], ya);
      yb = fmaf(x2.y, ET[9], yb);
      yc = fmaf(x2.z, ET[10], yc);
      yd = fmaf(x2.w, ET[11], yd);
      float yh = (ya + yb) + (yc + yd);
      float y = yh + dppf<0xB1>(yh);               // combine pair halves
      float msg = __logf(y) + am;
      u_prev = msg - cum;
      umax = fmaxf(umax, u_prev);

      // combine pair halves of ring partial -> drest for step t+1
      drest = part + dppf<0xB1>(part);

      // ---- lagged LSE-scale update (off critical path, every 4 steps)
      if ((p & 3) == 3) {
        float mm = active ? msg : NEGF;
        mm = fmaxf(mm, dppf<0x121>(mm));
        mm = fmaxf(mm, dppf<0x122>(mm));
        mm = fmaxf(mm, dppf<0x124>(mm));
        mm = fmaxf(mm, dppf<0x128>(mm));
        mm = fmaxf(mm, __shfl_xor(mm, 16));
        mm = fmaxf(mm, __shfl_xor(mm, 32));
        am = __int_as_float(__builtin_amdgcn_readfirstlane(__float_as_int(mm)));
      }

      // ---- finalize (wave-uniform branch): partition = am + log sum_c x[c]
      if (t == len) {
        float S = ((x0.x + x0.y) + (x0.z + x0.w)) +
                  ((x1.x + x1.y) + (x1.z + x1.w)) +
                  ((x2.x + x2.y) + (x2.z + x2.w));
        S = S + dppf<0xB1>(S);
        if (l == 0) out[b] = __logf(S) + am;
        goto finish;
      }

      // ---- prefetch queue advance (at odd i, load pair starting at even i+5)
      if (p & 1) {
        int ia = t + 4;  // i + 5 = (t-1) + 5
        if (ia > TT - 2) ia = TT - 2;
        Q0 = Q1;
        Q1 = Q2;
        Q2 = *(const float2*)(sp + ia);
      }
      ++t;
    }
  }
finish:;
}

extern "C" void kernel_launch(void* const* d_in, const int* in_sizes, int n_in,
                              void* d_out, int out_size, void* d_ws, size_t ws_size,
                              hipStream_t stream) {
  const float* hs = (const float*)d_in[0];     // (B,T,H) f32
  const float* W = (const float*)d_in[1];      // (H,C) f32
  const float* bias = (const float*)d_in[2];   // (C,) f32
  const float* trans = (const float*)d_in[3];  // (C,C) f32
  const float* db = (const float*)d_in[4];     // (K,C) f32
  const int* lengths = (const int*)d_in[5];    // (B,) i32
  float* scoresT = (float*)d_ws;               // (B,C,T) f32 = 12.6 MB scratch

  score_gemm<<<(BB * TT) / 256, 256, 0, stream>>>(hs, W, bias, scoresT);
  crf_scan<<<BB, 64, 0, stream>>>(scoresT, trans, db, lengths, (float*)d_out);
}